// Round 1
// baseline (1998.409 us; speedup 1.0000x reference)
//
#include <hip/hip_runtime.h>

// Sizes (from reference): N=500000, C=128, H=256, A=10, E=600000, B=50000.
// N%32==0, B%16==0 -> no tail guards needed in gemm/mlp.

// ---- degree count: deg (int) += 1 per incoming edge -------------------------
__global__ __launch_bounds__(256) void k_deg(const int* __restrict__ dst, int E,
                                             int* __restrict__ deg) {
    int e = blockIdx.x * 256 + threadIdx.x;
    if (e < E) atomicAdd(&deg[dst[e]], 1);
}

// ---- dinv = rsqrt(deg + 1)  (in-place int->float) ---------------------------
__global__ __launch_bounds__(256) void k_dinv(float* __restrict__ dinv, int N) {
    int i = blockIdx.x * 256 + threadIdx.x;
    if (i < N) {
        int c = ((const int*)dinv)[i];
        dinv[i] = rsqrtf((float)c + 1.0f);
    }
}

// ---- xw = state @ W  (N x 128) @ (128 x 128), fp32 vector -------------------
// 32 rows per block, 256 threads, 4x4 per-thread tile. W read from L2 (64KB).
__global__ __launch_bounds__(256) void k_gemm(const float* __restrict__ X,
                                              const float* __restrict__ W,
                                              float* __restrict__ Y, int N) {
    __shared__ float xs[32 * 128];  // 16 KB
    size_t brow = (size_t)blockIdx.x * 32;
    // stage 32 rows of X: 1024 float4s across 256 threads
    {
        const float4* Xv = (const float4*)(X + brow * 128);
        float4* sv = (float4*)xs;
        #pragma unroll
        for (int j = 0; j < 4; j++)
            sv[threadIdx.x + j * 256] = Xv[threadIdx.x + j * 256];
    }
    __syncthreads();
    int tc = threadIdx.x & 31;   // 32 col groups of 4
    int tr = threadIdx.x >> 5;   // 8 row groups of 4
    int c0 = tc * 4, r0 = tr * 4;
    float acc[4][4] = {};
    #pragma unroll 4
    for (int k = 0; k < 128; k++) {
        float4 b = *(const float4*)(W + k * 128 + c0);
        #pragma unroll
        for (int i = 0; i < 4; i++) {
            float a = xs[(r0 + i) * 128 + k];
            acc[i][0] += a * b.x;
            acc[i][1] += a * b.y;
            acc[i][2] += a * b.z;
            acc[i][3] += a * b.w;
        }
    }
    #pragma unroll
    for (int i = 0; i < 4; i++) {
        float4 o = {acc[i][0], acc[i][1], acc[i][2], acc[i][3]};
        *(float4*)(Y + (brow + r0 + i) * 128 + c0) = o;
    }
}

// ---- edge scatter: agg[dst] += dinv[src]*dinv[dst] * xw[src] ----------------
// 32 lanes per edge, float4 gather, 4 scalar fp32 atomics per lane.
__global__ __launch_bounds__(256) void k_scatter(const int* __restrict__ src,
                                                 const int* __restrict__ dst,
                                                 const float* __restrict__ dinv,
                                                 const float* __restrict__ xw,
                                                 float* __restrict__ agg, int E) {
    int t = blockIdx.x * 256 + threadIdx.x;
    int e = t >> 5;
    if (e >= E) return;
    int lane = t & 31;
    int s = src[e], d = dst[e];
    float nrm = dinv[s] * dinv[d];
    float4 v = *(const float4*)(xw + (size_t)s * 128 + lane * 4);
    float* p = agg + (size_t)d * 128 + lane * 4;
    atomicAdd(p + 0, v.x * nrm);
    atomicAdd(p + 1, v.y * nrm);
    atomicAdd(p + 2, v.z * nrm);
    atomicAdd(p + 3, v.w * nrm);
}

// ---- fused: relu(agg + dinv^2*xw + b_gcn) + state, action-weighted sum ------
__global__ __launch_bounds__(128) void k_readout(const float* __restrict__ agg,
                                                 const float* __restrict__ xw,
                                                 const float* __restrict__ state,
                                                 const float* __restrict__ dinv,
                                                 const float* __restrict__ bgcn,
                                                 const float* __restrict__ action,
                                                 float* __restrict__ xB, int B) {
    int b = blockIdx.x;
    int c = threadIdx.x;
    float bg = bgcn[c];
    float acc = 0.f;
    #pragma unroll
    for (int a = 0; a < 10; a++) {
        size_t n = (size_t)b * 10 + a;
        float di = dinv[n];
        float v = agg[n * 128 + c] + di * di * xw[n * 128 + c] + bg;
        v = fmaxf(v, 0.f) + state[n * 128 + c];
        acc += v * (action[b * 10 + a] * 10.f);
    }
    xB[(size_t)b * 128 + c] = acc;
}

// ---- MLP head: relu(x@W1+b1) -> relu(@W2+b2) -> @W3+b3 ----------------------
// 16 rows per block, 256 threads (one output column each), h tiles in LDS.
__global__ __launch_bounds__(256) void k_mlp(const float* __restrict__ xB,
                                             const float* __restrict__ W1,
                                             const float* __restrict__ b1,
                                             const float* __restrict__ W2,
                                             const float* __restrict__ b2,
                                             const float* __restrict__ W3,
                                             const float* __restrict__ b3,
                                             float* __restrict__ out, int B) {
    __shared__ float xs[16 * 128];   // 8 KB
    __shared__ float hs[16 * 256];   // 16 KB
    __shared__ float red[16 * 4];
    int r0 = blockIdx.x * 16;
    int tid = threadIdx.x;
    {
        const float4* xv = (const float4*)(xB + (size_t)r0 * 128);
        float4* sv = (float4*)xs;
        sv[tid] = xv[tid];
        sv[tid + 256] = xv[tid + 256];
    }
    __syncthreads();
    float acc[16];
    #pragma unroll
    for (int r = 0; r < 16; r++) acc[r] = 0.f;
    for (int k = 0; k < 128; k++) {
        float w = W1[k * 256 + tid];
        #pragma unroll
        for (int r = 0; r < 16; r++) acc[r] += xs[r * 128 + k] * w;
    }
    {
        float bb = b1[tid];
        #pragma unroll
        for (int r = 0; r < 16; r++) hs[r * 256 + tid] = fmaxf(acc[r] + bb, 0.f);
    }
    __syncthreads();
    #pragma unroll
    for (int r = 0; r < 16; r++) acc[r] = 0.f;
    for (int k = 0; k < 256; k++) {
        float w = W2[k * 256 + tid];
        #pragma unroll
        for (int r = 0; r < 16; r++) acc[r] += hs[r * 256 + k] * w;
    }
    {
        float bb = b2[tid];
        float w3 = W3[tid];
        #pragma unroll
        for (int r = 0; r < 16; r++) {
            float g = fmaxf(acc[r] + bb, 0.f) * w3;
            #pragma unroll
            for (int off = 32; off; off >>= 1) g += __shfl_down(g, off);
            if ((tid & 63) == 0) red[r * 4 + (tid >> 6)] = g;
        }
    }
    __syncthreads();
    if (tid < 16) {
        out[r0 + tid] = red[tid * 4] + red[tid * 4 + 1] + red[tid * 4 + 2] +
                        red[tid * 4 + 3] + b3[0];
    }
}

extern "C" void kernel_launch(void* const* d_in, const int* in_sizes, int n_in,
                              void* d_out, int out_size, void* d_ws, size_t ws_size,
                              hipStream_t stream) {
    const float* state  = (const float*)d_in[0];
    const int*   edge   = (const int*)d_in[1];   // [2, E] row-major: src then dst
    const float* action = (const float*)d_in[2];
    const float* W_gcn  = (const float*)d_in[3];
    const float* b_gcn  = (const float*)d_in[4];
    const float* W1     = (const float*)d_in[5];
    const float* b1     = (const float*)d_in[6];
    const float* W2     = (const float*)d_in[7];
    const float* b2     = (const float*)d_in[8];
    const float* W3     = (const float*)d_in[9];
    const float* b3     = (const float*)d_in[10];
    float* out = (float*)d_out;

    int N = in_sizes[0] / 128;
    int E = in_sizes[1] / 2;
    int B = out_size;
    const int* e_src = edge;
    const int* e_dst = edge + E;

    // workspace carve-up (fp32): xw[N*128] | agg[N*128] | dinv[N] | xB[B*128]
    float* xw   = (float*)d_ws;
    float* agg  = xw + (size_t)N * 128;
    float* dinv = agg + (size_t)N * 128;
    float* xB   = dinv + N;

    hipMemsetAsync(agg, 0, (size_t)N * 128 * sizeof(float), stream);
    hipMemsetAsync(dinv, 0, (size_t)N * sizeof(float), stream);

    k_deg<<<(E + 255) / 256, 256, 0, stream>>>(e_dst, E, (int*)dinv);
    k_dinv<<<(N + 255) / 256, 256, 0, stream>>>(dinv, N);
    k_gemm<<<N / 32, 256, 0, stream>>>(state, W_gcn, xw, N);
    k_scatter<<<(E * 32 + 255) / 256, 256, 0, stream>>>(e_src, e_dst, dinv, xw,
                                                        agg, E);
    k_readout<<<B, 128, 0, stream>>>(agg, xw, state, dinv, b_gcn, action, xB, B);
    k_mlp<<<B / 16, 256, 0, stream>>>(xB, W1, b1, W2, b2, W3, b3, out, B);
}

// Round 2
// 1035.503 us; speedup vs baseline: 1.9299x; 1.9299x over previous
//
#include <hip/hip_runtime.h>

// Sizes (from reference): N=500000, C=128, H=256, A=10, E=600000, B=50000.
// Strategy: no scatter-atomics. Build per-dst adjacency as an atomic linked
// list (avg degree 1.2), then gather+aggregate fused into the readout.

// ---- degree count -----------------------------------------------------------
__global__ __launch_bounds__(256) void k_deg(const int* __restrict__ dst, int E,
                                             int* __restrict__ deg) {
    int e = blockIdx.x * 256 + threadIdx.x;
    if (e < E) atomicAdd(&deg[dst[e]], 1);
}

// ---- dinv = rsqrt(deg + 1)  (+1 = self loop) --------------------------------
__global__ __launch_bounds__(256) void k_dinv(const int* __restrict__ deg,
                                              float* __restrict__ dinv, int N) {
    int i = blockIdx.x * 256 + threadIdx.x;
    if (i < N) dinv[i] = rsqrtf((float)deg[i] + 1.0f);
}

// ---- adjacency linked list: next[e] = atomicExch(&head[dst[e]], e) ----------
__global__ __launch_bounds__(256) void k_link(const int* __restrict__ dst, int E,
                                              int* __restrict__ head,
                                              int* __restrict__ nxt) {
    int e = blockIdx.x * 256 + threadIdx.x;
    if (e < E) nxt[e] = atomicExch(&head[dst[e]], e);
}

// ---- xw = state @ W  (N x 128) @ (128 x 128), fp32 vector -------------------
__global__ __launch_bounds__(256) void k_gemm(const float* __restrict__ X,
                                              const float* __restrict__ W,
                                              float* __restrict__ Y, int N) {
    __shared__ float xs[32 * 128];  // 16 KB
    size_t brow = (size_t)blockIdx.x * 32;
    {
        const float4* Xv = (const float4*)(X + brow * 128);
        float4* sv = (float4*)xs;
        #pragma unroll
        for (int j = 0; j < 4; j++)
            sv[threadIdx.x + j * 256] = Xv[threadIdx.x + j * 256];
    }
    __syncthreads();
    int tc = threadIdx.x & 31;
    int tr = threadIdx.x >> 5;
    int c0 = tc * 4, r0 = tr * 4;
    float acc[4][4] = {};
    #pragma unroll 4
    for (int k = 0; k < 128; k++) {
        float4 b = *(const float4*)(W + k * 128 + c0);
        #pragma unroll
        for (int i = 0; i < 4; i++) {
            float a = xs[(r0 + i) * 128 + k];
            acc[i][0] += a * b.x;
            acc[i][1] += a * b.y;
            acc[i][2] += a * b.z;
            acc[i][3] += a * b.w;
        }
    }
    #pragma unroll
    for (int i = 0; i < 4; i++) {
        float4 o = {acc[i][0], acc[i][1], acc[i][2], acc[i][3]};
        *(float4*)(Y + (brow + r0 + i) * 128 + c0) = o;
    }
}

// ---- fused aggregate + relu + residual + action-weighted readout ------------
// One block per output row b (10 nodes), 128 threads = channels.
__global__ __launch_bounds__(128) void k_readout(const int* __restrict__ head,
                                                 const int* __restrict__ nxt,
                                                 const int* __restrict__ e_src,
                                                 const float* __restrict__ dinv,
                                                 const float* __restrict__ xw,
                                                 const float* __restrict__ state,
                                                 const float* __restrict__ bgcn,
                                                 const float* __restrict__ action,
                                                 float* __restrict__ xB, int B) {
    int b = blockIdx.x;
    int c = threadIdx.x;
    float bg = bgcn[c];
    float acc = 0.f;
    #pragma unroll
    for (int a = 0; a < 10; a++) {
        int n = b * 10 + a;
        float di = dinv[n];
        // self-loop term: dinv[n]^2 * xw[n]
        float v = di * di * xw[(size_t)n * 128 + c];
        // in-edges via linked list (scalar walk, broadcast loads)
        for (int j = head[n]; j >= 0; j = nxt[j]) {
            int s = e_src[j];
            v += dinv[s] * di * xw[(size_t)s * 128 + c];
        }
        v = fmaxf(v + bg, 0.f) + state[(size_t)n * 128 + c];
        acc += v * (action[b * 10 + a] * 10.f);
    }
    xB[(size_t)b * 128 + c] = acc;
}

// ---- MLP head: relu(x@W1+b1) -> relu(@W2+b2) -> @W3+b3 ----------------------
__global__ __launch_bounds__(256) void k_mlp(const float* __restrict__ xB,
                                             const float* __restrict__ W1,
                                             const float* __restrict__ b1,
                                             const float* __restrict__ W2,
                                             const float* __restrict__ b2,
                                             const float* __restrict__ W3,
                                             const float* __restrict__ b3,
                                             float* __restrict__ out, int B) {
    __shared__ float xs[16 * 128];   // 8 KB
    __shared__ float hs[16 * 256];   // 16 KB
    __shared__ float red[16 * 4];
    int r0 = blockIdx.x * 16;
    int tid = threadIdx.x;
    {
        const float4* xv = (const float4*)(xB + (size_t)r0 * 128);
        float4* sv = (float4*)xs;
        sv[tid] = xv[tid];
        sv[tid + 256] = xv[tid + 256];
    }
    __syncthreads();
    float acc[16];
    #pragma unroll
    for (int r = 0; r < 16; r++) acc[r] = 0.f;
    for (int k = 0; k < 128; k++) {
        float w = W1[k * 256 + tid];
        #pragma unroll
        for (int r = 0; r < 16; r++) acc[r] += xs[r * 128 + k] * w;
    }
    {
        float bb = b1[tid];
        #pragma unroll
        for (int r = 0; r < 16; r++) hs[r * 256 + tid] = fmaxf(acc[r] + bb, 0.f);
    }
    __syncthreads();
    #pragma unroll
    for (int r = 0; r < 16; r++) acc[r] = 0.f;
    for (int k = 0; k < 256; k++) {
        float w = W2[k * 256 + tid];
        #pragma unroll
        for (int r = 0; r < 16; r++) acc[r] += hs[r * 256 + k] * w;
    }
    {
        float bb = b2[tid];
        float w3 = W3[tid];
        #pragma unroll
        for (int r = 0; r < 16; r++) {
            float g = fmaxf(acc[r] + bb, 0.f) * w3;
            #pragma unroll
            for (int off = 32; off; off >>= 1) g += __shfl_down(g, off);
            if ((tid & 63) == 0) red[r * 4 + (tid >> 6)] = g;
        }
    }
    __syncthreads();
    if (tid < 16) {
        out[r0 + tid] = red[tid * 4] + red[tid * 4 + 1] + red[tid * 4 + 2] +
                        red[tid * 4 + 3] + b3[0];
    }
}

extern "C" void kernel_launch(void* const* d_in, const int* in_sizes, int n_in,
                              void* d_out, int out_size, void* d_ws, size_t ws_size,
                              hipStream_t stream) {
    const float* state  = (const float*)d_in[0];
    const int*   edge   = (const int*)d_in[1];   // [2, E]: src row then dst row
    const float* action = (const float*)d_in[2];
    const float* W_gcn  = (const float*)d_in[3];
    const float* b_gcn  = (const float*)d_in[4];
    const float* W1     = (const float*)d_in[5];
    const float* b1     = (const float*)d_in[6];
    const float* W2     = (const float*)d_in[7];
    const float* b2     = (const float*)d_in[8];
    const float* W3     = (const float*)d_in[9];
    const float* b3     = (const float*)d_in[10];
    float* out = (float*)d_out;

    int N = in_sizes[0] / 128;
    int E = in_sizes[1] / 2;
    int B = out_size;
    const int* e_src = edge;
    const int* e_dst = edge + E;

    // workspace: xw[N*128] f32 | xB[B*128] f32 | dinv[N] f32 | deg[N] i32
    //            head[N] i32 | next[E] i32
    float* xw   = (float*)d_ws;
    float* xB   = xw + (size_t)N * 128;
    float* dinv = xB + (size_t)B * 128;
    int*   deg  = (int*)(dinv + N);
    int*   head = deg + N;
    int*   nxt  = head + N;

    hipMemsetAsync(deg, 0, (size_t)N * sizeof(int), stream);
    hipMemsetAsync(head, 0xFF, (size_t)N * sizeof(int), stream);  // -1

    k_deg<<<(E + 255) / 256, 256, 0, stream>>>(e_dst, E, deg);
    k_dinv<<<(N + 255) / 256, 256, 0, stream>>>(deg, dinv, N);
    k_link<<<(E + 255) / 256, 256, 0, stream>>>(e_dst, E, head, nxt);
    k_gemm<<<N / 32, 256, 0, stream>>>(state, W_gcn, xw, N);
    k_readout<<<B, 128, 0, stream>>>(head, nxt, e_src, dinv, xw, state, b_gcn,
                                     action, xB, B);
    k_mlp<<<B / 16, 256, 0, stream>>>(xB, W1, b1, W2, b2, W3, b3, out, B);
}

// Round 3
// 799.455 us; speedup vs baseline: 2.4997x; 1.2953x over previous
//
#include <hip/hip_runtime.h>

// Sizes: N=500000, C=128, H=256, A=10, E=600000, B=50000.
// R3: bf16 MFMA for GEMM + MLP, xw stored bf16 (L3-resident gathers),
// gather-linked-list aggregation fused into readout.

typedef __bf16 bf16x8 __attribute__((ext_vector_type(8)));
typedef float f32x4 __attribute__((ext_vector_type(4)));

// ---- degree count -----------------------------------------------------------
__global__ __launch_bounds__(256) void k_deg(const int* __restrict__ dst, int E,
                                             int* __restrict__ deg) {
    int e = blockIdx.x * 256 + threadIdx.x;
    if (e < E) atomicAdd(&deg[dst[e]], 1);
}

// ---- dinv = rsqrt(deg + 1)  (+1 = self loop) --------------------------------
__global__ __launch_bounds__(256) void k_dinv(const int* __restrict__ deg,
                                              float* __restrict__ dinv, int N) {
    int i = blockIdx.x * 256 + threadIdx.x;
    if (i < N) dinv[i] = rsqrtf((float)deg[i] + 1.0f);
}

// ---- adjacency linked list --------------------------------------------------
__global__ __launch_bounds__(256) void k_link(const int* __restrict__ dst, int E,
                                              int* __restrict__ head,
                                              int* __restrict__ nxt) {
    int e = blockIdx.x * 256 + threadIdx.x;
    if (e < E) nxt[e] = atomicExch(&head[dst[e]], e);
}

// ---- transpose-convert weights: Wt[n*K+k] = bf16(W[k*Nc+n]) -----------------
// K is a power of two; kbits = log2(K).
__global__ __launch_bounds__(256) void k_tconv(const float* __restrict__ W,
                                               __bf16* __restrict__ Wt,
                                               int kbits, int total, int Nc) {
    int i = blockIdx.x * 256 + threadIdx.x;
    if (i < total) {
        int n = i >> kbits;
        int k = i & ((1 << kbits) - 1);
        Wt[i] = (__bf16)W[(long)k * Nc + n];
    }
}

// ---- xw = bf16( state @ W_gcn )  via MFMA 16x16x32 bf16 ---------------------
// 4 waves/block, each wave computes a 16-row x 128-col strip.
__global__ __launch_bounds__(256) void k_gemm(const float* __restrict__ X,
                                              const __bf16* __restrict__ Wt,
                                              __bf16* __restrict__ Y, int N) {
    int wave = threadIdx.x >> 6;
    int lane = threadIdx.x & 63;
    long row0 = (long)blockIdx.x * 64 + wave * 16;
    if (row0 >= N) return;
    int m = lane & 15;
    int quad = lane >> 4;
    f32x4 acc[8] = {};
    #pragma unroll
    for (int kt = 0; kt < 4; kt++) {
        int k0 = kt * 32 + quad * 8;
        const float* ap = X + (row0 + m) * 128 + k0;
        float4 lo = *(const float4*)ap;
        float4 hi = *(const float4*)(ap + 4);
        bf16x8 a = {(__bf16)lo.x, (__bf16)lo.y, (__bf16)lo.z, (__bf16)lo.w,
                    (__bf16)hi.x, (__bf16)hi.y, (__bf16)hi.z, (__bf16)hi.w};
        #pragma unroll
        for (int t = 0; t < 8; t++) {
            bf16x8 b = *(const bf16x8*)(Wt + (t * 16 + m) * 128 + k0);
            acc[t] = __builtin_amdgcn_mfma_f32_16x16x32_bf16(a, b, acc[t], 0, 0, 0);
        }
    }
    #pragma unroll
    for (int t = 0; t < 8; t++)
        #pragma unroll
        for (int r = 0; r < 4; r++)
            Y[(row0 + quad * 4 + r) * 128 + t * 16 + m] = (__bf16)acc[t][r];
}

// ---- fused aggregate + relu + residual + action-weighted readout ------------
__global__ __launch_bounds__(128) void k_readout(const int* __restrict__ head,
                                                 const int* __restrict__ nxt,
                                                 const int* __restrict__ e_src,
                                                 const float* __restrict__ dinv,
                                                 const __bf16* __restrict__ xw,
                                                 const float* __restrict__ state,
                                                 const float* __restrict__ bgcn,
                                                 const float* __restrict__ action,
                                                 __bf16* __restrict__ xB, int B) {
    int b = blockIdx.x;
    int c = threadIdx.x;
    float bg = bgcn[c];
    float acc = 0.f;
    #pragma unroll
    for (int a = 0; a < 10; a++) {
        int n = b * 10 + a;
        float di = dinv[n];
        float v = di * di * (float)xw[(size_t)n * 128 + c];
        for (int j = head[n]; j >= 0; j = nxt[j]) {
            int s = e_src[j];
            v += dinv[s] * di * (float)xw[(size_t)s * 128 + c];
        }
        v = fmaxf(v + bg, 0.f) + state[(size_t)n * 128 + c];
        acc += v * (action[b * 10 + a] * 10.f);
    }
    xB[(size_t)b * 128 + c] = (__bf16)acc;
}

// ---- MLP head via MFMA: relu(x@W1+b1) -> relu(@W2+b2) -> @W3+b3 -------------
// 16 rows/block, 4 waves each owning 64 output cols; h1 in padded LDS.
__global__ __launch_bounds__(256) void k_mlp(const __bf16* __restrict__ xB,
                                             const __bf16* __restrict__ W1t,
                                             const float* __restrict__ b1,
                                             const __bf16* __restrict__ W2t,
                                             const float* __restrict__ b2,
                                             const float* __restrict__ W3,
                                             const float* __restrict__ b3,
                                             float* __restrict__ out, int B) {
    __shared__ __bf16 hs[16][264];   // 264 = 256 + 8 pad (bank-friendly)
    __shared__ float osum[4][16];
    int wave = threadIdx.x >> 6;
    int lane = threadIdx.x & 63;
    int m = lane & 15;
    int quad = lane >> 4;
    long r0 = (long)blockIdx.x * 16;

    // layer 1: h1[16 x 256], this wave: cols wave*64 .. +63
    f32x4 acc[4] = {};
    #pragma unroll
    for (int kt = 0; kt < 4; kt++) {
        int k0 = kt * 32 + quad * 8;
        bf16x8 a = *(const bf16x8*)(xB + (r0 + m) * 128 + k0);
        #pragma unroll
        for (int t = 0; t < 4; t++) {
            int n = wave * 64 + t * 16 + m;
            bf16x8 b = *(const bf16x8*)(W1t + (long)n * 128 + k0);
            acc[t] = __builtin_amdgcn_mfma_f32_16x16x32_bf16(a, b, acc[t], 0, 0, 0);
        }
    }
    #pragma unroll
    for (int t = 0; t < 4; t++) {
        int n = wave * 64 + t * 16 + m;
        float bb = b1[n];
        #pragma unroll
        for (int r = 0; r < 4; r++)
            hs[quad * 4 + r][n] = (__bf16)fmaxf(acc[t][r] + bb, 0.f);
    }
    __syncthreads();

    // layer 2: K=256
    f32x4 acc2[4] = {};
    #pragma unroll
    for (int kt = 0; kt < 8; kt++) {
        int k0 = kt * 32 + quad * 8;
        bf16x8 a = *(const bf16x8*)(&hs[m][k0]);
        #pragma unroll
        for (int t = 0; t < 4; t++) {
            int n = wave * 64 + t * 16 + m;
            bf16x8 b = *(const bf16x8*)(W2t + (long)n * 256 + k0);
            acc2[t] = __builtin_amdgcn_mfma_f32_16x16x32_bf16(a, b, acc2[t], 0, 0, 0);
        }
    }

    // layer 3: out[r] = sum_n relu(h2)[r][n] * W3[n]
    float part[4] = {0.f, 0.f, 0.f, 0.f};
    #pragma unroll
    for (int t = 0; t < 4; t++) {
        int n = wave * 64 + t * 16 + m;
        float bb = b2[n], w3 = W3[n];
        #pragma unroll
        for (int r = 0; r < 4; r++)
            part[r] += fmaxf(acc2[t][r] + bb, 0.f) * w3;
    }
    #pragma unroll
    for (int off = 8; off; off >>= 1)
        #pragma unroll
        for (int r = 0; r < 4; r++)
            part[r] += __shfl_down(part[r], off, 16);
    if (m == 0) {
        #pragma unroll
        for (int r = 0; r < 4; r++) osum[wave][quad * 4 + r] = part[r];
    }
    __syncthreads();
    if (threadIdx.x < 16)
        out[r0 + threadIdx.x] = osum[0][threadIdx.x] + osum[1][threadIdx.x] +
                                osum[2][threadIdx.x] + osum[3][threadIdx.x] + b3[0];
}

extern "C" void kernel_launch(void* const* d_in, const int* in_sizes, int n_in,
                              void* d_out, int out_size, void* d_ws, size_t ws_size,
                              hipStream_t stream) {
    const float* state  = (const float*)d_in[0];
    const int*   edge   = (const int*)d_in[1];   // [2, E]: src row then dst row
    const float* action = (const float*)d_in[2];
    const float* W_gcn  = (const float*)d_in[3];
    const float* b_gcn  = (const float*)d_in[4];
    const float* W1     = (const float*)d_in[5];
    const float* b1     = (const float*)d_in[6];
    const float* W2     = (const float*)d_in[7];
    const float* b2     = (const float*)d_in[8];
    const float* W3     = (const float*)d_in[9];
    const float* b3     = (const float*)d_in[10];
    float* out = (float*)d_out;

    int N = in_sizes[0] / 128;
    int E = in_sizes[1] / 2;
    int B = out_size;
    const int* e_src = edge;
    const int* e_dst = edge + E;

    // workspace: xw bf16[N*128] | xB bf16[B*128] | Wgt bf16[128*128]
    //          | W1t bf16[256*128] | W2t bf16[256*256]
    //          | dinv f32[N] | deg i32[N] | head i32[N] | nxt i32[E]
    __bf16* xw  = (__bf16*)d_ws;
    __bf16* xB  = xw + (size_t)N * 128;
    __bf16* Wgt = xB + (size_t)B * 128;
    __bf16* W1t = Wgt + 128 * 128;
    __bf16* W2t = W1t + 256 * 128;
    float* dinv = (float*)(W2t + 256 * 256);
    int*   deg  = (int*)(dinv + N);
    int*   head = deg + N;
    int*   nxt  = head + N;

    hipMemsetAsync(deg, 0, (size_t)N * sizeof(int), stream);
    hipMemsetAsync(head, 0xFF, (size_t)N * sizeof(int), stream);  // -1

    k_tconv<<<(128 * 128 + 255) / 256, 256, 0, stream>>>(W_gcn, Wgt, 7, 128 * 128, 128);
    k_tconv<<<(256 * 128 + 255) / 256, 256, 0, stream>>>(W1, W1t, 7, 256 * 128, 256);
    k_tconv<<<(256 * 256 + 255) / 256, 256, 0, stream>>>(W2, W2t, 8, 256 * 256, 256);
    k_deg<<<(E + 255) / 256, 256, 0, stream>>>(e_dst, E, deg);
    k_dinv<<<(N + 255) / 256, 256, 0, stream>>>(deg, dinv, N);
    k_link<<<(E + 255) / 256, 256, 0, stream>>>(e_dst, E, head, nxt);
    k_gemm<<<(N + 63) / 64, 256, 0, stream>>>(state, Wgt, xw, N);
    k_readout<<<B, 128, 0, stream>>>(head, nxt, e_src, dinv, xw, state, b_gcn,
                                     action, xB, B);
    k_mlp<<<B / 16, 256, 0, stream>>>(xB, W1t, b1, W2t, b2, W3, b3, out, B);
}

// Round 4
// 701.365 us; speedup vs baseline: 2.8493x; 1.1399x over previous
//
#include <hip/hip_runtime.h>

// Sizes: N=500000, C=128, H=256, A=10, E=600000, B=50000.
// R4: wide-load readout (16B/lane), xw pre-scaled by dinv[src] in gemm
// epilogue (dinv factors out of aggregation), merged deg+link kernel.

typedef __bf16 bf16x8 __attribute__((ext_vector_type(8)));
typedef float f32x4 __attribute__((ext_vector_type(4)));

// ---- per-edge: degree count + adjacency linked list -------------------------
__global__ __launch_bounds__(256) void k_edges(const int* __restrict__ dst, int E,
                                               int* __restrict__ deg,
                                               int* __restrict__ head,
                                               int* __restrict__ nxt) {
    int e = blockIdx.x * 256 + threadIdx.x;
    if (e < E) {
        int d = dst[e];
        atomicAdd(&deg[d], 1);
        nxt[e] = atomicExch(&head[d], e);
    }
}

// ---- dinv = rsqrt(deg + 1)  (+1 = self loop) --------------------------------
__global__ __launch_bounds__(256) void k_dinv(const int* __restrict__ deg,
                                              float* __restrict__ dinv, int N) {
    int i = blockIdx.x * 256 + threadIdx.x;
    if (i < N) dinv[i] = rsqrtf((float)deg[i] + 1.0f);
}

// ---- transpose-convert weights: Wt[n*K+k] = bf16(W[k*Nc+n]) -----------------
__global__ __launch_bounds__(256) void k_tconv(const float* __restrict__ W,
                                               __bf16* __restrict__ Wt,
                                               int kbits, int total, int Nc) {
    int i = blockIdx.x * 256 + threadIdx.x;
    if (i < total) {
        int n = i >> kbits;
        int k = i & ((1 << kbits) - 1);
        Wt[i] = (__bf16)W[(long)k * Nc + n];
    }
}

// ---- xws = bf16( dinv[row] * (state @ W_gcn) )  via MFMA 16x16x32 bf16 ------
__global__ __launch_bounds__(256) void k_gemm(const float* __restrict__ X,
                                              const __bf16* __restrict__ Wt,
                                              const float* __restrict__ dinv,
                                              __bf16* __restrict__ Y, int N) {
    int wave = threadIdx.x >> 6;
    int lane = threadIdx.x & 63;
    long row0 = (long)blockIdx.x * 64 + wave * 16;
    if (row0 >= N) return;
    int m = lane & 15;
    int quad = lane >> 4;
    f32x4 acc[8] = {};
    #pragma unroll
    for (int kt = 0; kt < 4; kt++) {
        int k0 = kt * 32 + quad * 8;
        const float* ap = X + (row0 + m) * 128 + k0;
        float4 lo = *(const float4*)ap;
        float4 hi = *(const float4*)(ap + 4);
        bf16x8 a = {(__bf16)lo.x, (__bf16)lo.y, (__bf16)lo.z, (__bf16)lo.w,
                    (__bf16)hi.x, (__bf16)hi.y, (__bf16)hi.z, (__bf16)hi.w};
        #pragma unroll
        for (int t = 0; t < 8; t++) {
            bf16x8 b = *(const bf16x8*)(Wt + (t * 16 + m) * 128 + k0);
            acc[t] = __builtin_amdgcn_mfma_f32_16x16x32_bf16(a, b, acc[t], 0, 0, 0);
        }
    }
    float dv[4];
    #pragma unroll
    for (int r = 0; r < 4; r++) dv[r] = dinv[row0 + quad * 4 + r];
    #pragma unroll
    for (int t = 0; t < 8; t++)
        #pragma unroll
        for (int r = 0; r < 4; r++)
            Y[(row0 + quad * 4 + r) * 128 + t * 16 + m] =
                (__bf16)(acc[t][r] * dv[r]);
}

// ---- fused aggregate + relu + residual + action-weighted readout ------------
// One block per b. 128 thr = 8 node slots x 16 lanes; lane owns 8 channels.
__global__ __launch_bounds__(128) void k_readout(const int* __restrict__ head,
                                                 const int* __restrict__ nxt,
                                                 const int* __restrict__ e_src,
                                                 const float* __restrict__ dinv,
                                                 const __bf16* __restrict__ xws,
                                                 const float* __restrict__ state,
                                                 const float* __restrict__ bgcn,
                                                 const float* __restrict__ action,
                                                 __bf16* __restrict__ xB, int B) {
    __shared__ float red[16][8];
    int b = blockIdx.x;
    int tid = threadIdx.x;
    int lane16 = tid & 15;
    int slot = tid >> 4;       // 0..7
    int c0 = lane16 * 8;
    float4 bg0 = *(const float4*)(bgcn + c0);
    float4 bg1 = *(const float4*)(bgcn + c0 + 4);
    float bg[8] = {bg0.x, bg0.y, bg0.z, bg0.w, bg1.x, bg1.y, bg1.z, bg1.w};
    float acc[8] = {};
    for (int a = slot; a < 10; a += 8) {
        int n = b * 10 + a;
        // sum of pre-scaled rows: self + in-edges (dinv[n] factored out)
        float s[8];
        bf16x8 x = *(const bf16x8*)(xws + (size_t)n * 128 + c0);
        #pragma unroll
        for (int k = 0; k < 8; k++) s[k] = (float)x[k];
        for (int j = head[n]; j >= 0; j = nxt[j]) {
            int sr = e_src[j];
            bf16x8 g = *(const bf16x8*)(xws + (size_t)sr * 128 + c0);
            #pragma unroll
            for (int k = 0; k < 8; k++) s[k] += (float)g[k];
        }
        float di = dinv[n];
        float aw = action[n] * 10.f;
        float4 st0 = *(const float4*)(state + (size_t)n * 128 + c0);
        float4 st1 = *(const float4*)(state + (size_t)n * 128 + c0 + 4);
        float st[8] = {st0.x, st0.y, st0.z, st0.w, st1.x, st1.y, st1.z, st1.w};
        #pragma unroll
        for (int k = 0; k < 8; k++)
            acc[k] += aw * (fmaxf(di * s[k] + bg[k], 0.f) + st[k]);
    }
    // reduce 8 slots -> 1: shuffle over slots within wave, LDS across waves
    #pragma unroll
    for (int k = 0; k < 8; k++) {
        acc[k] += __shfl_down(acc[k], 32);
        acc[k] += __shfl_down(acc[k], 16);
    }
    if (tid >= 64 && tid < 80) {
        #pragma unroll
        for (int k = 0; k < 8; k++) red[tid - 64][k] = acc[k];
    }
    __syncthreads();
    if (tid < 16) {
        bf16x8 o;
        #pragma unroll
        for (int k = 0; k < 8; k++) o[k] = (__bf16)(acc[k] + red[tid][k]);
        *(bf16x8*)(xB + (size_t)b * 128 + c0) = o;
    }
}

// ---- MLP head via MFMA: relu(x@W1+b1) -> relu(@W2+b2) -> @W3+b3 -------------
__global__ __launch_bounds__(256) void k_mlp(const __bf16* __restrict__ xB,
                                             const __bf16* __restrict__ W1t,
                                             const float* __restrict__ b1,
                                             const __bf16* __restrict__ W2t,
                                             const float* __restrict__ b2,
                                             const float* __restrict__ W3,
                                             const float* __restrict__ b3,
                                             float* __restrict__ out, int B) {
    __shared__ __bf16 hs[16][264];
    __shared__ float osum[4][16];
    int wave = threadIdx.x >> 6;
    int lane = threadIdx.x & 63;
    int m = lane & 15;
    int quad = lane >> 4;
    long r0 = (long)blockIdx.x * 16;

    f32x4 acc[4] = {};
    #pragma unroll
    for (int kt = 0; kt < 4; kt++) {
        int k0 = kt * 32 + quad * 8;
        bf16x8 a = *(const bf16x8*)(xB + (r0 + m) * 128 + k0);
        #pragma unroll
        for (int t = 0; t < 4; t++) {
            int n = wave * 64 + t * 16 + m;
            bf16x8 b = *(const bf16x8*)(W1t + (long)n * 128 + k0);
            acc[t] = __builtin_amdgcn_mfma_f32_16x16x32_bf16(a, b, acc[t], 0, 0, 0);
        }
    }
    #pragma unroll
    for (int t = 0; t < 4; t++) {
        int n = wave * 64 + t * 16 + m;
        float bb = b1[n];
        #pragma unroll
        for (int r = 0; r < 4; r++)
            hs[quad * 4 + r][n] = (__bf16)fmaxf(acc[t][r] + bb, 0.f);
    }
    __syncthreads();

    f32x4 acc2[4] = {};
    #pragma unroll
    for (int kt = 0; kt < 8; kt++) {
        int k0 = kt * 32 + quad * 8;
        bf16x8 a = *(const bf16x8*)(&hs[m][k0]);
        #pragma unroll
        for (int t = 0; t < 4; t++) {
            int n = wave * 64 + t * 16 + m;
            bf16x8 b = *(const bf16x8*)(W2t + (long)n * 256 + k0);
            acc2[t] = __builtin_amdgcn_mfma_f32_16x16x32_bf16(a, b, acc2[t], 0, 0, 0);
        }
    }

    float part[4] = {0.f, 0.f, 0.f, 0.f};
    #pragma unroll
    for (int t = 0; t < 4; t++) {
        int n = wave * 64 + t * 16 + m;
        float bb = b2[n], w3 = W3[n];
        #pragma unroll
        for (int r = 0; r < 4; r++)
            part[r] += fmaxf(acc2[t][r] + bb, 0.f) * w3;
    }
    #pragma unroll
    for (int off = 8; off; off >>= 1)
        #pragma unroll
        for (int r = 0; r < 4; r++)
            part[r] += __shfl_down(part[r], off, 16);
    if (m == 0) {
        #pragma unroll
        for (int r = 0; r < 4; r++) osum[wave][quad * 4 + r] = part[r];
    }
    __syncthreads();
    if (threadIdx.x < 16)
        out[r0 + threadIdx.x] = osum[0][threadIdx.x] + osum[1][threadIdx.x] +
                                osum[2][threadIdx.x] + osum[3][threadIdx.x] + b3[0];
}

extern "C" void kernel_launch(void* const* d_in, const int* in_sizes, int n_in,
                              void* d_out, int out_size, void* d_ws, size_t ws_size,
                              hipStream_t stream) {
    const float* state  = (const float*)d_in[0];
    const int*   edge   = (const int*)d_in[1];   // [2, E]: src row then dst row
    const float* action = (const float*)d_in[2];
    const float* W_gcn  = (const float*)d_in[3];
    const float* b_gcn  = (const float*)d_in[4];
    const float* W1     = (const float*)d_in[5];
    const float* b1     = (const float*)d_in[6];
    const float* W2     = (const float*)d_in[7];
    const float* b2     = (const float*)d_in[8];
    const float* W3     = (const float*)d_in[9];
    const float* b3     = (const float*)d_in[10];
    float* out = (float*)d_out;

    int N = in_sizes[0] / 128;
    int E = in_sizes[1] / 2;
    int B = out_size;
    const int* e_src = edge;
    const int* e_dst = edge + E;

    // workspace: xws bf16[N*128] | xB bf16[B*128] | Wgt bf16[128*128]
    //          | W1t bf16[256*128] | W2t bf16[256*256]
    //          | dinv f32[N] | deg i32[N] | head i32[N] | nxt i32[E]
    __bf16* xws = (__bf16*)d_ws;
    __bf16* xB  = xws + (size_t)N * 128;
    __bf16* Wgt = xB + (size_t)B * 128;
    __bf16* W1t = Wgt + 128 * 128;
    __bf16* W2t = W1t + 256 * 128;
    float* dinv = (float*)(W2t + 256 * 256);
    int*   deg  = (int*)(dinv + N);
    int*   head = deg + N;
    int*   nxt  = head + N;

    hipMemsetAsync(deg, 0, (size_t)N * sizeof(int), stream);
    hipMemsetAsync(head, 0xFF, (size_t)N * sizeof(int), stream);  // -1

    k_tconv<<<(128 * 128 + 255) / 256, 256, 0, stream>>>(W_gcn, Wgt, 7, 128 * 128, 128);
    k_tconv<<<(256 * 128 + 255) / 256, 256, 0, stream>>>(W1, W1t, 7, 256 * 128, 256);
    k_tconv<<<(256 * 256 + 255) / 256, 256, 0, stream>>>(W2, W2t, 8, 256 * 256, 256);
    k_edges<<<(E + 255) / 256, 256, 0, stream>>>(e_dst, E, deg, head, nxt);
    k_dinv<<<(N + 255) / 256, 256, 0, stream>>>(deg, dinv, N);
    k_gemm<<<(N + 63) / 64, 256, 0, stream>>>(state, Wgt, dinv, xws, N);
    k_readout<<<B, 128, 0, stream>>>(head, nxt, e_src, dinv, xws, state, b_gcn,
                                     action, xB, B);
    k_mlp<<<B / 16, 256, 0, stream>>>(xB, W1t, b1, W2t, b2, W3, b3, out, B);
}